// Round 18
// baseline (65.950 us; speedup 1.0000x reference)
//
#include <hip/hip_runtime.h>
#include <math.h>

#define T_    2048
#define BTOK  4096   // B * T
#define NSLOT 48     // strips 0-15: 1 split; strips 16-31: 2 splits

namespace {
constexpr int GRADE[16] = {0,1,1,1,1,2,2,2,2,2,2,3,3,3,3,4};
constexpr int AUGK[16]  = {-1,5,-1,-1,-1,6,6,6,-1,-1,-1,7,7,7,-1,8};
constexpr int AUGS[16]  = { 0,0, 0, 0, 0,2,3,4, 0, 0, 0,8,9,10,0,14};
constexpr float FINNER[16] = {1.f,0.f,1.f,1.f,1.f,0.f,0.f,0.f,1.f,1.f,1.f,0.f,0.f,0.f,1.f,0.f};
}

typedef __attribute__((ext_vector_type(4))) _Float16 h4_t;
typedef __attribute__((ext_vector_type(4))) float    f4_t;

__device__ __forceinline__ unsigned pkh(float a, float b){
  return __builtin_bit_cast(unsigned, __builtin_amdgcn_cvt_pkrtz(a,b));
}
__device__ __forceinline__ f4_t mfma16(h4_t a, h4_t b, f4_t c){
  return __builtin_amdgcn_mfma_f32_16x16x16f16(a,b,c,0,0,0);
}

__device__ __forceinline__ float gelu_f(float v){
  return 0.5f*v*(1.f + erff(v*0.70710678118654752f));
}

__device__ __forceinline__ int rsign_d(int a, int b){
  int s=0; a>>=1; while(a){ s += __popc(a&b); a>>=1; } return (s&1) ? -1 : 1;
}

// ---- K_A: embed + in-linear + norm + QKV projections + fp16 pack ---------
// 64 threads = 2 tokens x 32 lanes (8 heads x 4 input-quarters).
__global__ void __launch_bounds__(64) k_in(
    const float* __restrict__ x,
    const float* __restrict__ w_in_mv, const float* __restrict__ b_in_mv,
    const float* __restrict__ w_in_m2s, const float* __restrict__ b_in_s,
    const float* __restrict__ w_mv, const float* __restrict__ w_s2mv,
    const float* __restrict__ w_m2s, const float* __restrict__ w_s2s,
    float* __restrict__ h_mv, float* __restrict__ h_s,
    unsigned* __restrict__ qph, unsigned* __restrict__ kph, unsigned* __restrict__ vph)
{
  __shared__ float NS[2*152];   // per token: n_mv 128 + n_s 24
  int tid=threadIdx.x, tl=tid>>5, ln=tid&31;
  int o=ln&7, iq=ln>>3;          // iq 0..3
  int tt=blockIdx.x*2+tl;
  int b=tt>>11, t=tt&(T_-1);
  const float* xp = x+(size_t)tt*6;
  float mv[16];
  #pragma unroll
  for(int p=0;p<16;p++) mv[p]=0.f;
  mv[0]=1.f; mv[14]=1.f;
  mv[13]=-xp[0]; mv[12]=xp[1]; mv[11]=-xp[2];
  mv[5]=0.5f*xp[3]; mv[6]=0.5f*xp[4]; mv[7]=0.5f*xp[5];

  const float* wo=w_in_mv+o*9;
  float h[16]; float sq=0.f;
  #pragma unroll
  for(int p=0;p<16;p++){
    float v=wo[GRADE[p]]*mv[p];
    if(AUGK[p]>=0) v+=wo[AUGK[p]]*mv[AUGS[p]];
    if(p==0) v+=b_in_mv[o];
    h[p]=v; sq+=FINNER[p]*v*v;
  }
  sq+=__shfl_xor(sq,1); sq+=__shfl_xor(sq,2); sq+=__shfl_xor(sq,4);
  float dmv=rsqrtf(sq*0.125f+0.01f);
  float hs[3]; float ssq=0.f;
  #pragma unroll
  for(int jj=0;jj<3;jj++){ float v=w_in_m2s[o*3+jj]+b_in_s[o*3+jj]; hs[jj]=v; ssq+=v*v; }
  ssq+=__shfl_xor(ssq,1); ssq+=__shfl_xor(ssq,2); ssq+=__shfl_xor(ssq,4);
  float dss=rsqrtf(ssq*(1.f/24.f)+0.01f);

  float* ns=&NS[tl*152];
  if(iq==0){
    float4* hg=(float4*)(h_mv+(size_t)tt*128+o*16);
    hg[0]=make_float4(h[0],h[1],h[2],h[3]);
    hg[1]=make_float4(h[4],h[5],h[6],h[7]);
    hg[2]=make_float4(h[8],h[9],h[10],h[11]);
    hg[3]=make_float4(h[12],h[13],h[14],h[15]);
    #pragma unroll
    for(int jj=0;jj<3;jj++) h_s[(size_t)tt*24+o*3+jj]=hs[jj];
    #pragma unroll
    for(int p=0;p<16;p++) ns[o*16+p]=h[p]*dmv;
    #pragma unroll
    for(int jj=0;jj<3;jj++) ns[128+o*3+jj]=hs[jj]*dss;
  }
  __syncthreads();

  // projections: lane (o,iq) does input channels iq*2..+1, scalar j iq*6..+5
  float yq[16],yk[16],yv[16];
  #pragma unroll
  for(int p=0;p<16;p++){ yq[p]=0.f; yk[p]=0.f; yv[p]=0.f; }
  float nx0p[2];
  const float* wq=w_mv+o*72;
  #pragma unroll
  for(int ii=0;ii<2;ii++){
    int i=iq*2+ii;
    float xi[16];
    const float4* xs4=(const float4*)&ns[i*16];
    #pragma unroll
    for(int r4=0;r4<4;r4++){ float4 v=xs4[r4]; xi[r4*4]=v.x; xi[r4*4+1]=v.y; xi[r4*4+2]=v.z; xi[r4*4+3]=v.w; }
    nx0p[ii]=xi[0];
    const float* aq=wq+i*9; const float* ak=aq+576; const float* av=aq+1152;
    #pragma unroll
    for(int p=0;p<16;p++){
      float bb=xi[p];
      yq[p]+=aq[GRADE[p]]*bb; yk[p]+=ak[GRADE[p]]*bb; yv[p]+=av[GRADE[p]]*bb;
      if(AUGK[p]>=0){
        float au=xi[AUGS[p]];
        yq[p]+=aq[AUGK[p]]*au; yk[p]+=ak[AUGK[p]]*au; yv[p]+=av[AUGK[p]]*au;
      }
    }
  }
  float sq3[3]={0,0,0}, sk3[3]={0,0,0}, sv3[3]={0,0,0};
  float eq=0.f,ek=0.f,ev=0.f;
  for(int j=iq*6;j<iq*6+6;j++){
    float s=ns[128+j];
    eq+=w_s2mv[o*24+j]*s; ek+=w_s2mv[192+o*24+j]*s; ev+=w_s2mv[384+o*24+j]*s;
    #pragma unroll
    for(int jj=0;jj<3;jj++){
      int d=o*3+jj;
      sq3[jj]+=w_s2s[d*24+j]*s;
      sk3[jj]+=w_s2s[576+d*24+j]*s;
      sv3[jj]+=w_s2s[1152+d*24+j]*s;
    }
  }
  #pragma unroll
  for(int ii=0;ii<2;ii++){
    int i=iq*2+ii;
    #pragma unroll
    for(int jj=0;jj<3;jj++){
      int d=o*3+jj;
      sq3[jj]+=w_m2s[d*8+i]*nx0p[ii];
      sk3[jj]+=w_m2s[192+d*8+i]*nx0p[ii];
      sv3[jj]+=w_m2s[384+d*8+i]*nx0p[ii];
    }
  }
  yq[0]+=eq; yk[0]+=ek; yv[0]+=ev;
  #pragma unroll
  for(int p=0;p<16;p++){
    yq[p]+=__shfl_xor(yq[p],8);  yq[p]+=__shfl_xor(yq[p],16);
    yk[p]+=__shfl_xor(yk[p],8);  yk[p]+=__shfl_xor(yk[p],16);
    yv[p]+=__shfl_xor(yv[p],8);  yv[p]+=__shfl_xor(yv[p],16);
  }
  #pragma unroll
  for(int jj=0;jj<3;jj++){
    sq3[jj]+=__shfl_xor(sq3[jj],8); sq3[jj]+=__shfl_xor(sq3[jj],16);
    sk3[jj]+=__shfl_xor(sk3[jj],8); sk3[jj]+=__shfl_xor(sk3[jj],16);
    sv3[jj]+=__shfl_xor(sv3[jj],8); sv3[jj]+=__shfl_xor(sv3[jj],16);
  }

  const float scale = 0.3015113445777636f;  // 1/sqrt(11)
  size_t rb=((size_t)(b*8+o)*T_+t);
  if(iq==0){
    uint4 qa,qb;
    qa.x=pkh(yq[0]*scale, yq[2]*scale);  qa.y=pkh(yq[3]*scale, yq[4]*scale);
    qa.z=pkh(yq[8]*scale, yq[9]*scale);  qa.w=pkh(yq[10]*scale, yq[14]*scale);
    qb.x=pkh(sq3[0]*scale, sq3[1]*scale); qb.y=pkh(sq3[2]*scale, 0.f); qb.z=0u; qb.w=0u;
    uint4* qr4=(uint4*)qph + rb*2; qr4[0]=qa; qr4[1]=qb;
  } else if(iq==1){
    uint4 ka,kb;
    ka.x=pkh(yk[0],yk[2]);  ka.y=pkh(yk[3],yk[4]);
    ka.z=pkh(yk[8],yk[9]);  ka.w=pkh(yk[10],yk[14]);
    kb.x=pkh(sk3[0],sk3[1]); kb.y=pkh(sk3[2],0.f); kb.z=0u; kb.w=0u;
    uint4* kr4=(uint4*)kph + rb*2; kr4[0]=ka; kr4[1]=kb;
  }
  // V^T chunk-tiled write: tile = 256 u32 = [comp][8 pairs]
  {
    size_t vbase2 = (size_t)(b*8+o)*(T_/16)*256;   // per-bh: T/16 chunk tiles
    size_t cidx   = (size_t)(t>>4);                // chunk index
    int    wp     = (t>>1)&7;                      // pair within chunk
    size_t tb     = vbase2 + cidx*256;
    bool even = (tl==0);
    if(iq==2){
      #pragma unroll
      for(int c=0;c<10;c++){
        float other=__shfl_xor(yv[c],32);
        if(even) vph[tb + c*8 + wp]=pkh(yv[c],other);
      }
    } else if(iq==3){
      #pragma unroll
      for(int c=10;c<16;c++){
        float other=__shfl_xor(yv[c],32);
        if(even) vph[tb + c*8 + wp]=pkh(yv[c],other);
      }
      #pragma unroll
      for(int jj=0;jj<3;jj++){
        float other=__shfl_xor(sv3[jj],32);
        if(even) vph[tb + (16+jj)*8 + wp]=pkh(sv3[jj],other);
      }
      if(even) vph[tb + 19*8 + wp]=0x3C003C00u;  // half2(1,1) -> l
    }
    if(even){  // zero-fill comps 20..31 (poison safety)
      int c0=20+iq*3;
      #pragma unroll
      for(int cc=0;cc<3;cc++) vph[tb + (c0+cc)*8 + wp]=0u;
    }
  }
}

// ---- K_B: MFMA attention, no-max softmax, additive partials --------------
// Block = 4 waves x 16 queries. NSLOT=48: strips 0-15 unsplit, 16-31 2-way.
// All 768 blocks co-resident; deep loops (<=64 chunks) pipeline loads.
__global__ void __launch_bounds__(256) k_attn(
    const unsigned* __restrict__ qph, const unsigned* __restrict__ kph,
    const unsigned* __restrict__ vph,
    float* __restrict__ part)
{
  int tid=threadIdx.x;
  int wave=tid>>6, lane=tid&63;
  int col=lane&15, rowb=lane>>4;   // mfma col / k-block
  int j=blockIdx.x;
  int bh=j&15;
  int z=NSLOT-1-(j>>4);            // heavy slots first
  int strip, sp, c;
  if(z<16){ strip=z; sp=0; c=1; }
  else { int rem=z-16; strip=16+(rem>>1); sp=rem&1; c=2; }
  int nchunk = (strip+1)*4;        // 16-key chunks in [0,(strip+1)*64)
  int t0 = sp*nchunk/c, t1 = (sp+1)*nchunk/c;
  int chend = strip*4 + wave + 1;  // causal cap for this wave's 16-query tile
  if (t1 < chend) chend = t1;

  int q0 = strip*64 + wave*16;
  const h4_t* qh4=(const h4_t*)qph;
  const h4_t* kh4=(const h4_t*)kph;
  const h4_t* vh4=(const h4_t*)vph;

  // B=Q operand: lane holds Q[q0+col][d=4*rowb+i]
  h4_t bq = qh4[((size_t)bh*T_ + q0 + col)*4 + rowb];

  f4_t acc0={0.f,0.f,0.f,0.f}, acc1={0.f,0.f,0.f,0.f};
  size_t vtile = (size_t)bh*(T_/16)*128;   // h4 units: 128 h4 per chunk tile
  int voff0 = col*4 + rowb;                // comps 0..15
  int voff1 = 64 + col*4 + rowb;           // comps 16..31

  #pragma unroll 4
  for(int ch=t0; ch<chend; ++ch){
    // A=K operand: lane holds K[16ch+col][d=4*rowb+i]
    h4_t ak = kh4[((size_t)bh*T_ + 16*ch + col)*4 + rowb];
    f4_t zz={0.f,0.f,0.f,0.f};
    f4_t st = mfma16(ak, bq, zz);    // S^T[key=4*rowb+r][q=col]
    float c0=fminf(__expf(st[0]),60000.f);
    float c1=fminf(__expf(st[1]),60000.f);
    float c2=fminf(__expf(st[2]),60000.f);
    float c3=fminf(__expf(st[3]),60000.f);
    h4_t bp = __builtin_bit_cast(h4_t, make_uint2(pkh(c0,c1), pkh(c2,c3)));
    // A=V^T operands: contiguous per-chunk tiles
    h4_t av0 = vh4[vtile + (size_t)ch*128 + voff0];
    h4_t av1 = vh4[vtile + (size_t)ch*128 + voff1];
    acc0 = mfma16(av0, bp, acc0);
    acc1 = mfma16(av1, bp, acc1);
  }

  // write partials: O^T[comp=4*rowb+r][q=q0w+col]; comps 16..19 from acc1 (rowb==0)
  float* rec = part + (((size_t)bh*NSLOT + z)*64 + wave*16 + col)*20;
  ((float4*)rec)[rowb] = make_float4(acc0[0],acc0[1],acc0[2],acc0[3]);
  if(rowb==0) ((float4*)rec)[4] = make_float4(acc1[0],acc1[1],acc1[2],acc1[3]);
}

// ---- K_C: combine partials + ao + norm + m1 + GP/join + m2 + out ---------
// 64 threads = 2 tokens x 32 lanes (8 channels x 4 quarters).
__global__ void __launch_bounds__(64) k_tail(
    const float* __restrict__ part,
    const float* __restrict__ w_ao_mv, const float* __restrict__ w_ao_s2mv,
    const float* __restrict__ w_ao_m2s, const float* __restrict__ w_ao_s2s,
    const float* __restrict__ b_ao_mv, const float* __restrict__ b_ao_s,
    const float* __restrict__ h_mv, const float* __restrict__ h_s,
    const float* __restrict__ w_m1_mv, const float* __restrict__ w_m1_s2mv,
    const float* __restrict__ w_m1_m2s, const float* __restrict__ w_m1_s2s,
    const float* __restrict__ b_m1_mv, const float* __restrict__ b_m1_s,
    const float* __restrict__ w_m2_mv, const float* __restrict__ w_m2_s2mv,
    const float* __restrict__ b_m2_mv,
    const float* __restrict__ w_out_mv,
    float* __restrict__ out)
{
  __shared__ int   GPI[256]; __shared__ float GPS[256];
  __shared__ int   JNI[256]; __shared__ float JNS[256];
  __shared__ float OS[2*152];
  __shared__ float NS[2*152];
  __shared__ float U[2*264];
  __shared__ float G[2*136];
  __shared__ float GSm[2*24];
  int tid=threadIdx.x, tl=tid>>5, ln=tid&31;
  int o=ln&7, iq=ln>>3;          // iq 0..3
  int tt=blockIdx.x*2+tl;

  { // build tables (threads 0..31)
    const int mask_of[16]={0,1,2,4,8,3,5,9,6,10,12,7,11,13,14,15};
    const int idx_of[16] ={0,1,2,5,3,6,8,11,4,7,9,12,10,13,14,15};
    if (tid<16){
      int k=tid, km=mask_of[k], slotn=0;
      for(int i=0;i<16;i++){
        int im=mask_of[i], jm=im^km;
        if(im & jm & 1) continue;
        GPI[k*16+slotn]=i|(idx_of[jm]<<4);
        GPS[k*16+slotn]=(float)rsign_d(im,jm);
        slotn++;
      }
      for(;slotn<16;slotn++){ GPI[k*16+slotn]=0; GPS[k*16+slotn]=0.f; }
    } else if (tid<32){
      int p=tid-16, pm=mask_of[p], rest=15&~pm, slotn=0;
      for(int u=0;u<16;u++){
        if(u & ~rest) continue;
        int am=pm|u, bm=pm|(rest&~u);
        float s=(float)( rsign_d(pm,15&~pm)*rsign_d(15&~am,15&~bm)
                        *rsign_d(am,15&~am)*rsign_d(bm,15&~bm) );
        JNI[p*16+slotn]=idx_of[am]|(idx_of[bm]<<4);
        JNS[p*16+slotn]=s;
        slotn++;
      }
      for(;slotn<16;slotn++){ JNI[p*16+slotn]=0; JNS[p*16+slotn]=0.f; }
    }
  }

  // combine attention partials: lane = (head h=ln>>2, quarter qr=ln&3)
  // strips of 64 queries; nsp=(strip>>4)+1; rbase = strip<16? strip : 16+2*(strip-16)
  {
    int b=tt>>11, t=tt&(T_-1);
    int strip=t>>6, qil=t&63;
    int h=ln>>2, qr=ln&3;
    int nsp=(strip>>4)+1;
    int rbase=(strip<16)? strip : 16+2*(strip-16);
    const float* pb = part + ((size_t)((b*8+h)*NSLOT+rbase)*64 + qil)*20;
    float am[4]={0,0,0,0};
    float lv=0.f, s0=0.f, s1=0.f, s2=0.f;
    for(int spp=0; spp<nsp; ++spp){
      const float4* p4=(const float4*)(pb + (size_t)spp*64*20);
      float4 a4=p4[qr];
      am[0]+=a4.x; am[1]+=a4.y; am[2]+=a4.z; am[3]+=a4.w;
      if(qr==0){ float4 meta=p4[4]; s0+=meta.x; s1+=meta.y; s2+=meta.z; lv+=meta.w; }
    }
    float inv = (qr==0)? 1.f/lv : 0.f;
    inv = __shfl(inv, (tid & ~3));
    float* os=&OS[tl*152];
    #pragma unroll
    for(int p=0;p<4;p++) os[h*16+qr*4+p]=am[p]*inv;
    if(qr==0){ os[128+h*3]=s0*inv; os[128+h*3+1]=s1*inv; os[128+h*3+2]=s2*inv; }
  }
  __syncthreads();

  const float* os=&OS[tl*152];
  float xh[2][16];
  #pragma unroll
  for(int ii=0;ii<2;ii++){
    #pragma unroll
    for(int p=0;p<16;p++) xh[ii][p]=os[(iq*2+ii)*16+p];
  }
  float xs[24];
  #pragma unroll
  for(int jj=0;jj<24;jj++) xs[jj]=os[128+jj];

  // ao: channel o, input quarter iq
  float y[16];
  #pragma unroll
  for(int p=0;p<16;p++) y[p]=0.f;
  #pragma unroll
  for(int ii=0;ii<2;ii++){
    const float* wi=w_ao_mv+o*72+(iq*2+ii)*9;
    #pragma unroll
    for(int p=0;p<16;p++){
      y[p]+=wi[GRADE[p]]*xh[ii][p];
      if(AUGK[p]>=0) y[p]+=wi[AUGK[p]]*xh[ii][AUGS[p]];
    }
  }
  float e=(iq==0)? b_ao_mv[o] : 0.f;
  for(int j2=iq*6;j2<iq*6+6;j2++) e+=w_ao_s2mv[o*24+j2]*xs[j2];
  y[0]+=e;
  float a3[3];
  #pragma unroll
  for(int jj=0;jj<3;jj++) a3[jj]=(iq==0)? b_ao_s[o*3+jj] : 0.f;
  #pragma unroll
  for(int ii=0;ii<2;ii++){
    #pragma unroll
    for(int jj=0;jj<3;jj++) a3[jj]+=w_ao_m2s[(o*3+jj)*8+(iq*2+ii)]*xh[ii][0];
  }
  for(int j2=iq*6;j2<iq*6+6;j2++){
    #pragma unroll
    for(int jj=0;jj<3;jj++) a3[jj]+=w_ao_s2s[(o*3+jj)*24+j2]*xs[j2];
  }
  #pragma unroll
  for(int p=0;p<16;p++){ y[p]+=__shfl_xor(y[p],8); y[p]+=__shfl_xor(y[p],16); }
  #pragma unroll
  for(int jj=0;jj<3;jj++){ a3[jj]+=__shfl_xor(a3[jj],8); a3[jj]+=__shfl_xor(a3[jj],16); }

  // residual + norms (dup across iq; reduce over o via xor 1,2,4)
  float hch[16]; float sqv=0.f;
  { const float4* hg=(const float4*)(h_mv+(size_t)tt*128+o*16);
    #pragma unroll
    for(int r4=0;r4<4;r4++){ float4 v=hg[r4];
      hch[r4*4]=v.x+y[r4*4]; hch[r4*4+1]=v.y+y[r4*4+1];
      hch[r4*4+2]=v.z+y[r4*4+2]; hch[r4*4+3]=v.w+y[r4*4+3]; } }
  #pragma unroll
  for(int p=0;p<16;p++) sqv+=FINNER[p]*hch[p]*hch[p];
  sqv+=__shfl_xor(sqv,1); sqv+=__shfl_xor(sqv,2); sqv+=__shfl_xor(sqv,4);
  float dmv=rsqrtf(sqv*0.125f+0.01f);
  float hs3[3]; float ssq=0.f;
  #pragma unroll
  for(int jj=0;jj<3;jj++){
    float v=h_s[(size_t)tt*24+o*3+jj]+a3[jj];
    hs3[jj]=v; ssq+=v*v;
  }
  ssq+=__shfl_xor(ssq,1); ssq+=__shfl_xor(ssq,2); ssq+=__shfl_xor(ssq,4);
  float dss=rsqrtf(ssq*(1.f/24.f)+0.01f);

  float* nsbuf=&NS[tl*152];
  if(iq==0){
    #pragma unroll
    for(int p=0;p<16;p++) nsbuf[o*16+p]=hch[p]*dmv;
    #pragma unroll
    for(int jj=0;jj<3;jj++) nsbuf[128+o*3+jj]=hs3[jj]*dss;
  }
  __syncthreads();

  // m1: lane = (output channel ln16, input half mh)
  {
    int ln16=ln&15, mh=ln>>4;
    float u[16];
    #pragma unroll
    for(int p=0;p<16;p++) u[p]=0.f;
    for(int i=mh*4;i<mh*4+4;i++){
      float xi[16];
      const float4* xs4=(const float4*)&nsbuf[i*16];
      #pragma unroll
      for(int r4=0;r4<4;r4++){ float4 v=xs4[r4]; xi[r4*4]=v.x; xi[r4*4+1]=v.y; xi[r4*4+2]=v.z; xi[r4*4+3]=v.w; }
      const float* wi=w_m1_mv+ln16*72+i*9;
      #pragma unroll
      for(int p=0;p<16;p++){
        u[p]+=wi[GRADE[p]]*xi[p];
        if(AUGK[p]>=0) u[p]+=wi[AUGK[p]]*xi[AUGS[p]];
      }
    }
    float e1=(mh==0)? b_m1_mv[ln16] : 0.f;
    for(int j2=mh*12;j2<mh*12+12;j2++) e1+=w_m1_s2mv[ln16*24+j2]*nsbuf[128+j2];
    u[0]+=e1;
    #pragma unroll
    for(int p=0;p<16;p++) u[p]+=__shfl_xor(u[p],16);
    if(mh==0){
      float* uu=&U[tl*264];
      #pragma unroll
      for(int p=0;p<16;p++) uu[ln16*16+p]=u[p];
    }
  }
  if(ln<8){  // m1 scalar path, o=ln
    float s3[3];
    #pragma unroll
    for(int jj=0;jj<3;jj++) s3[jj]=b_m1_s[o*3+jj];
    for(int j2=0;j2<24;j2++){
      float s=nsbuf[128+j2];
      #pragma unroll
      for(int jj=0;jj<3;jj++) s3[jj]+=w_m1_s2s[(o*3+jj)*24+j2]*s;
    }
    for(int i=0;i<8;i++){
      float x0=nsbuf[i*16];
      #pragma unroll
      for(int jj=0;jj<3;jj++) s3[jj]+=w_m1_m2s[(o*3+jj)*8+i]*x0;
    }
    #pragma unroll
    for(int jj=0;jj<3;jj++) GSm[tl*24+o*3+jj]=gelu_f(s3[jj]);
  }
  __syncthreads();

  // GP (o<4) / JOIN (o>=4): product o, component quarter iq; gate via shfl
  {
    const int*   TI=(o<4)? GPI : JNI;
    const float* TS=(o<4)? GPS : JNS;
    const float* uu=&U[tl*264];
    const float* lft=&uu[((o<4)? o : (4+o))*16];
    const float* rgt=&uu[((o<4)? (4+o) : (8+o))*16];
    float g[4];
    #pragma unroll
    for(int kk=0;kk<4;kk++){
      int k=iq*4+kk;
      float accv=0.f;
      #pragma unroll
      for(int e2=0;e2<16;e2++){
        int ij=TI[k*16+e2]; float sg=TS[k*16+e2];
        accv += sg * lft[ij&15] * rgt[ij>>4];
      }
      g[kk]=accv;
    }
    float g0 = __shfl(g[0], (tid & ~0x18));   // comp0 lives on iq==0 lane
    float gt = gelu_f(g0);
    float* gg=&G[tl*136];
    #pragma unroll
    for(int kk=0;kk<4;kk++) gg[o*16+iq*4+kk]=g[kk]*gt;
  }
  __syncthreads();

  // m2: channel o, input quarter iq
  float y2[16];
  #pragma unroll
  for(int p=0;p<16;p++) y2[p]=0.f;
  #pragma unroll
  for(int ii=0;ii<2;ii++){
    float xi[16];
    const float4* gi=(const float4*)&G[tl*136+(iq*2+ii)*16];
    #pragma unroll
    for(int r4=0;r4<4;r4++){ float4 v=gi[r4]; xi[r4*4]=v.x; xi[r4*4+1]=v.y; xi[r4*4+2]=v.z; xi[r4*4+3]=v.w; }
    const float* wi=w_m2_mv+o*72+(iq*2+ii)*9;
    #pragma unroll
    for(int p=0;p<16;p++){
      y2[p]+=wi[GRADE[p]]*xi[p];
      if(AUGK[p]>=0) y2[p]+=wi[AUGK[p]]*xi[AUGS[p]];
    }
  }
  float e2=(iq==0)? b_m2_mv[o] : 0.f;
  for(int j2=iq*6;j2<iq*6+6;j2++) e2+=w_m2_s2mv[o*24+j2]*GSm[tl*24+j2];
  y2[0]+=e2;
  #pragma unroll
  for(int p=0;p<16;p++){ y2[p]+=__shfl_xor(y2[p],8); y2[p]+=__shfl_xor(y2[p],16); }

  float hf[16];
  #pragma unroll
  for(int p=0;p<16;p++) hf[p]=hch[p]+y2[p];

  const float* wout=w_out_mv+o*9;
  float c5 =wout[2]*hf[5] +wout[6]*hf[2];
  float c6 =wout[2]*hf[6] +wout[6]*hf[3];
  float c7 =wout[2]*hf[7] +wout[6]*hf[4];
  float c11=wout[3]*hf[11]+wout[7]*hf[8];
  float c12=wout[3]*hf[12]+wout[7]*hf[9];
  float c13=wout[3]*hf[13]+wout[7]*hf[10];
  float c14=wout[3]*hf[14];
  #pragma unroll
  for(int mk=1; mk<8; mk<<=1){
    c5+=__shfl_xor(c5,mk); c6+=__shfl_xor(c6,mk); c7+=__shfl_xor(c7,mk);
    c11+=__shfl_xor(c11,mk); c12+=__shfl_xor(c12,mk);
    c13+=__shfl_xor(c13,mk); c14+=__shfl_xor(c14,mk);
  }
  if(ln==0){
    float dd=c14;
    dd=(fabsf(dd)>0.001f)? dd : (dd>=0.f? 0.001f : -0.001f);
    float* op=out+(size_t)tt*6;
    op[0]=-c13/dd; op[1]=c12/dd; op[2]=-c11/dd;
    op[3]=2.f*c5; op[4]=2.f*c6; op[5]=2.f*c7;
  }
}

extern "C" void kernel_launch(void* const* d_in, const int* in_sizes, int n_in,
                              void* d_out, int out_size, void* d_ws, size_t ws_size,
                              hipStream_t stream)
{
  (void)in_sizes; (void)n_in; (void)out_size; (void)ws_size;
  const float* x         =(const float*)d_in[0];
  const float* w_in_mv   =(const float*)d_in[1];
  const float* b_in_mv   =(const float*)d_in[2];
  const float* w_in_m2s  =(const float*)d_in[3];
  const float* b_in_s    =(const float*)d_in[4];
  const float* w_qkv_mv  =(const float*)d_in[5];
  const float* w_qkv_s2mv=(const float*)d_in[6];
  const float* w_qkv_m2s =(const float*)d_in[7];
  const float* w_qkv_s2s =(const float*)d_in[8];
  const float* w_ao_mv   =(const float*)d_in[9];
  const float* w_ao_s2mv =(const float*)d_in[10];
  const float* w_ao_m2s  =(const float*)d_in[11];
  const float* w_ao_s2s  =(const float*)d_in[12];
  const float* b_ao_mv   =(const float*)d_in[13];
  const float* b_ao_s    =(const float*)d_in[14];
  const float* w_m1_mv   =(const float*)d_in[15];
  const float* w_m1_s2mv =(const float*)d_in[16];
  const float* w_m1_m2s  =(const float*)d_in[17];
  const float* w_m1_s2s  =(const float*)d_in[18];
  const float* b_m1_mv   =(const float*)d_in[19];
  const float* b_m1_s    =(const float*)d_in[20];
  const float* w_m2_mv   =(const float*)d_in[21];
  const float* w_m2_s2mv =(const float*)d_in[22];
  const float* b_m2_mv   =(const float*)d_in[25];
  const float* w_out_mv  =(const float*)d_in[27];
  float* outp=(float*)d_out;

  float* ws=(float*)d_ws;
  size_t off=0;
  float* h_mv = ws+off; off+=(size_t)BTOK*128;
  float* h_s  = ws+off; off+=(size_t)BTOK*24;
  unsigned* qph = (unsigned*)(ws+off); off+=(size_t)16*T_*8;        // 16 halfs/token
  unsigned* kph = (unsigned*)(ws+off); off+=(size_t)16*T_*8;        // 16 halfs/token
  unsigned* vph = (unsigned*)(ws+off); off+=(size_t)16*(T_/16)*256; // V^T chunk tiles
  float* part = ws+off; off+=(size_t)16*NSLOT*64*20;

  k_in  <<<BTOK/2,64,0,stream>>>(x,w_in_mv,b_in_mv,w_in_m2s,b_in_s,
                                 w_qkv_mv,w_qkv_s2mv,w_qkv_m2s,w_qkv_s2s,
                                 h_mv,h_s,qph,kph,vph);
  k_attn<<<16*NSLOT,256,0,stream>>>(qph,kph,vph,part);
  k_tail<<<BTOK/2,64,0,stream>>>(part,
                                 w_ao_mv,w_ao_s2mv,w_ao_m2s,w_ao_s2s,b_ao_mv,b_ao_s,
                                 h_mv,h_s,
                                 w_m1_mv,w_m1_s2mv,w_m1_m2s,w_m1_s2s,b_m1_mv,b_m1_s,
                                 w_m2_mv,w_m2_s2mv,b_m2_mv,w_out_mv,outp);
}

// Round 19
// 58.390 us; speedup vs baseline: 1.1295x; 1.1295x over previous
//
#include <hip/hip_runtime.h>
#include <math.h>

#define T_    2048
#define BTOK  4096   // B * T
#define NSLOT 80     // sum over 32 strips of ceil((s+1)/8)

namespace {
constexpr int GRADE[16] = {0,1,1,1,1,2,2,2,2,2,2,3,3,3,3,4};
constexpr int AUGK[16]  = {-1,5,-1,-1,-1,6,6,6,-1,-1,-1,7,7,7,-1,8};
constexpr int AUGS[16]  = { 0,0, 0, 0, 0,2,3,4, 0, 0, 0,8,9,10,0,14};
constexpr float FINNER[16] = {1.f,0.f,1.f,1.f,1.f,0.f,0.f,0.f,1.f,1.f,1.f,0.f,0.f,0.f,1.f,0.f};
}

typedef __attribute__((ext_vector_type(4))) _Float16 h4_t;
typedef __attribute__((ext_vector_type(4))) float    f4_t;

__device__ __forceinline__ unsigned pkh(float a, float b){
  return __builtin_bit_cast(unsigned, __builtin_amdgcn_cvt_pkrtz(a,b));
}
__device__ __forceinline__ f4_t mfma16(h4_t a, h4_t b, f4_t c){
  return __builtin_amdgcn_mfma_f32_16x16x16f16(a,b,c,0,0,0);
}

__device__ __forceinline__ float gelu_f(float v){
  return 0.5f*v*(1.f + erff(v*0.70710678118654752f));
}

__device__ __forceinline__ int rsign_d(int a, int b){
  int s=0; a>>=1; while(a){ s += __popc(a&b); a>>=1; } return (s&1) ? -1 : 1;
}

// ---- K_A: embed + in-linear + norm + QKV projections + fp16 pack ---------
// 64 threads = 2 tokens x 32 lanes (8 heads x 4 input-quarters).
// Q/K: 16 halfs/token.
// V^T chunk-tiled: [bh][chunk=key/16][comp 0..31][8 pairs] u32 -> a wave's
// PV operand load is one contiguous 512B region.
__global__ void __launch_bounds__(64) k_in(
    const float* __restrict__ x,
    const float* __restrict__ w_in_mv, const float* __restrict__ b_in_mv,
    const float* __restrict__ w_in_m2s, const float* __restrict__ b_in_s,
    const float* __restrict__ w_mv, const float* __restrict__ w_s2mv,
    const float* __restrict__ w_m2s, const float* __restrict__ w_s2s,
    float* __restrict__ h_mv, float* __restrict__ h_s,
    unsigned* __restrict__ qph, unsigned* __restrict__ kph, unsigned* __restrict__ vph)
{
  __shared__ float NS[2*152];   // per token: n_mv 128 + n_s 24
  int tid=threadIdx.x, tl=tid>>5, ln=tid&31;
  int o=ln&7, iq=ln>>3;          // iq 0..3
  int tt=blockIdx.x*2+tl;
  int b=tt>>11, t=tt&(T_-1);
  const float* xp = x+(size_t)tt*6;
  float mv[16];
  #pragma unroll
  for(int p=0;p<16;p++) mv[p]=0.f;
  mv[0]=1.f; mv[14]=1.f;
  mv[13]=-xp[0]; mv[12]=xp[1]; mv[11]=-xp[2];
  mv[5]=0.5f*xp[3]; mv[6]=0.5f*xp[4]; mv[7]=0.5f*xp[5];

  const float* wo=w_in_mv+o*9;
  float h[16]; float sq=0.f;
  #pragma unroll
  for(int p=0;p<16;p++){
    float v=wo[GRADE[p]]*mv[p];
    if(AUGK[p]>=0) v+=wo[AUGK[p]]*mv[AUGS[p]];
    if(p==0) v+=b_in_mv[o];
    h[p]=v; sq+=FINNER[p]*v*v;
  }
  sq+=__shfl_xor(sq,1); sq+=__shfl_xor(sq,2); sq+=__shfl_xor(sq,4);
  float dmv=rsqrtf(sq*0.125f+0.01f);
  float hs[3]; float ssq=0.f;
  #pragma unroll
  for(int jj=0;jj<3;jj++){ float v=w_in_m2s[o*3+jj]+b_in_s[o*3+jj]; hs[jj]=v; ssq+=v*v; }
  ssq+=__shfl_xor(ssq,1); ssq+=__shfl_xor(ssq,2); ssq+=__shfl_xor(ssq,4);
  float dss=rsqrtf(ssq*(1.f/24.f)+0.01f);

  float* ns=&NS[tl*152];
  if(iq==0){
    float4* hg=(float4*)(h_mv+(size_t)tt*128+o*16);
    hg[0]=make_float4(h[0],h[1],h[2],h[3]);
    hg[1]=make_float4(h[4],h[5],h[6],h[7]);
    hg[2]=make_float4(h[8],h[9],h[10],h[11]);
    hg[3]=make_float4(h[12],h[13],h[14],h[15]);
    #pragma unroll
    for(int jj=0;jj<3;jj++) h_s[(size_t)tt*24+o*3+jj]=hs[jj];
    #pragma unroll
    for(int p=0;p<16;p++) ns[o*16+p]=h[p]*dmv;
    #pragma unroll
    for(int jj=0;jj<3;jj++) ns[128+o*3+jj]=hs[jj]*dss;
  }
  __syncthreads();

  // projections: lane (o,iq) does input channels iq*2..+1, scalar j iq*6..+5
  float yq[16],yk[16],yv[16];
  #pragma unroll
  for(int p=0;p<16;p++){ yq[p]=0.f; yk[p]=0.f; yv[p]=0.f; }
  float nx0p[2];
  const float* wq=w_mv+o*72;
  #pragma unroll
  for(int ii=0;ii<2;ii++){
    int i=iq*2+ii;
    float xi[16];
    const float4* xs4=(const float4*)&ns[i*16];
    #pragma unroll
    for(int r4=0;r4<4;r4++){ float4 v=xs4[r4]; xi[r4*4]=v.x; xi[r4*4+1]=v.y; xi[r4*4+2]=v.z; xi[r4*4+3]=v.w; }
    nx0p[ii]=xi[0];
    const float* aq=wq+i*9; const float* ak=aq+576; const float* av=aq+1152;
    #pragma unroll
    for(int p=0;p<16;p++){
      float bb=xi[p];
      yq[p]+=aq[GRADE[p]]*bb; yk[p]+=ak[GRADE[p]]*bb; yv[p]+=av[GRADE[p]]*bb;
      if(AUGK[p]>=0){
        float au=xi[AUGS[p]];
        yq[p]+=aq[AUGK[p]]*au; yk[p]+=ak[AUGK[p]]*au; yv[p]+=av[AUGK[p]]*au;
      }
    }
  }
  float sq3[3]={0,0,0}, sk3[3]={0,0,0}, sv3[3]={0,0,0};
  float eq=0.f,ek=0.f,ev=0.f;
  for(int j=iq*6;j<iq*6+6;j++){
    float s=ns[128+j];
    eq+=w_s2mv[o*24+j]*s; ek+=w_s2mv[192+o*24+j]*s; ev+=w_s2mv[384+o*24+j]*s;
    #pragma unroll
    for(int jj=0;jj<3;jj++){
      int d=o*3+jj;
      sq3[jj]+=w_s2s[d*24+j]*s;
      sk3[jj]+=w_s2s[576+d*24+j]*s;
      sv3[jj]+=w_s2s[1152+d*24+j]*s;
    }
  }
  #pragma unroll
  for(int ii=0;ii<2;ii++){
    int i=iq*2+ii;
    #pragma unroll
    for(int jj=0;jj<3;jj++){
      int d=o*3+jj;
      sq3[jj]+=w_m2s[d*8+i]*nx0p[ii];
      sk3[jj]+=w_m2s[192+d*8+i]*nx0p[ii];
      sv3[jj]+=w_m2s[384+d*8+i]*nx0p[ii];
    }
  }
  yq[0]+=eq; yk[0]+=ek; yv[0]+=ev;
  #pragma unroll
  for(int p=0;p<16;p++){
    yq[p]+=__shfl_xor(yq[p],8);  yq[p]+=__shfl_xor(yq[p],16);
    yk[p]+=__shfl_xor(yk[p],8);  yk[p]+=__shfl_xor(yk[p],16);
    yv[p]+=__shfl_xor(yv[p],8);  yv[p]+=__shfl_xor(yv[p],16);
  }
  #pragma unroll
  for(int jj=0;jj<3;jj++){
    sq3[jj]+=__shfl_xor(sq3[jj],8); sq3[jj]+=__shfl_xor(sq3[jj],16);
    sk3[jj]+=__shfl_xor(sk3[jj],8); sk3[jj]+=__shfl_xor(sk3[jj],16);
    sv3[jj]+=__shfl_xor(sv3[jj],8); sv3[jj]+=__shfl_xor(sv3[jj],16);
  }

  const float scale = 0.3015113445777636f;  // 1/sqrt(11)
  size_t rb=((size_t)(b*8+o)*T_+t);
  if(iq==0){
    uint4 qa,qb;
    qa.x=pkh(yq[0]*scale, yq[2]*scale);  qa.y=pkh(yq[3]*scale, yq[4]*scale);
    qa.z=pkh(yq[8]*scale, yq[9]*scale);  qa.w=pkh(yq[10]*scale, yq[14]*scale);
    qb.x=pkh(sq3[0]*scale, sq3[1]*scale); qb.y=pkh(sq3[2]*scale, 0.f); qb.z=0u; qb.w=0u;
    uint4* qr4=(uint4*)qph + rb*2; qr4[0]=qa; qr4[1]=qb;
  } else if(iq==1){
    uint4 ka,kb;
    ka.x=pkh(yk[0],yk[2]);  ka.y=pkh(yk[3],yk[4]);
    ka.z=pkh(yk[8],yk[9]);  ka.w=pkh(yk[10],yk[14]);
    kb.x=pkh(sk3[0],sk3[1]); kb.y=pkh(sk3[2],0.f); kb.z=0u; kb.w=0u;
    uint4* kr4=(uint4*)kph + rb*2; kr4[0]=ka; kr4[1]=kb;
  }
  // V^T chunk-tiled write: tile = 256 u32 = [comp][8 pairs]
  {
    size_t vbase2 = (size_t)(b*8+o)*(T_/16)*256;   // per-bh: T/16 chunk tiles
    size_t cidx   = (size_t)(t>>4);                // chunk index
    int    wp     = (t>>1)&7;                      // pair within chunk
    size_t tb     = vbase2 + cidx*256;
    bool even = (tl==0);
    if(iq==2){
      #pragma unroll
      for(int c=0;c<10;c++){
        float other=__shfl_xor(yv[c],32);
        if(even) vph[tb + c*8 + wp]=pkh(yv[c],other);
      }
    } else if(iq==3){
      #pragma unroll
      for(int c=10;c<16;c++){
        float other=__shfl_xor(yv[c],32);
        if(even) vph[tb + c*8 + wp]=pkh(yv[c],other);
      }
      #pragma unroll
      for(int jj=0;jj<3;jj++){
        float other=__shfl_xor(sv3[jj],32);
        if(even) vph[tb + (16+jj)*8 + wp]=pkh(sv3[jj],other);
      }
      if(even) vph[tb + 19*8 + wp]=0x3C003C00u;  // half2(1,1) -> l
    }
    if(even){  // zero-fill comps 20..31 (poison safety)
      int c0=20+iq*3;
      #pragma unroll
      for(int cc=0;cc<3;cc++) vph[tb + (c0+cc)*8 + wp]=0u;
    }
  }
}

// ---- K_B: MFMA attention, no-max softmax, additive partials --------------
// Block = 4 waves x 16 queries. V^T chunk-tiled: per-wave PV operand loads
// are contiguous 512B (comps 0-15) + 512B (comps 16-31) per chunk.
__global__ void __launch_bounds__(256) k_attn(
    const unsigned* __restrict__ qph, const unsigned* __restrict__ kph,
    const unsigned* __restrict__ vph,
    float* __restrict__ part)
{
  int tid=threadIdx.x;
  int wave=tid>>6, lane=tid&63;
  int col=lane&15, rowb=lane>>4;   // mfma col / k-block
  int j=blockIdx.x;
  int bh=j&15;
  int z=NSLOT-1-(j>>4);            // heavy slots first
  int a=0;
  while (4*(a+1)*(a+2) <= z) a++;  // groups of 8 strips share c=a+1
  int rem = z - 4*a*(a+1);
  int bqd = rem/(a+1);
  int sp  = rem - bqd*(a+1);
  int strip = 8*a + bqd;
  int c     = a+1;
  int nchunk = (strip+1)*4;        // 16-key chunks in [0,(strip+1)*64)
  int t0 = sp*nchunk/c, t1 = (sp+1)*nchunk/c;
  int chend = strip*4 + wave + 1;  // causal cap for this wave's 16-query tile
  if (t1 < chend) chend = t1;

  int q0 = strip*64 + wave*16;
  const h4_t* qh4=(const h4_t*)qph;
  const h4_t* kh4=(const h4_t*)kph;
  const h4_t* vh4=(const h4_t*)vph;

  // B=Q operand: lane holds Q[q0+col][d=4*rowb+i]
  h4_t bq = qh4[((size_t)bh*T_ + q0 + col)*4 + rowb];

  f4_t acc0={0.f,0.f,0.f,0.f}, acc1={0.f,0.f,0.f,0.f};
  size_t vtile = (size_t)bh*(T_/16)*128;   // h4 units: 128 h4 per chunk tile
  int voff0 = col*4 + rowb;                // comps 0..15
  int voff1 = 64 + col*4 + rowb;           // comps 16..31

  #pragma unroll 4
  for(int ch=t0; ch<chend; ++ch){
    // A=K operand: lane holds K[16ch+col][d=4*rowb+i]
    h4_t ak = kh4[((size_t)bh*T_ + 16*ch + col)*4 + rowb];
    f4_t zz={0.f,0.f,0.f,0.f};
    f4_t st = mfma16(ak, bq, zz);    // S^T[key=4*rowb+r][q=col]
    float c0=fminf(__expf(st[0]),60000.f);
    float c1=fminf(__expf(st[1]),60000.f);
    float c2=fminf(__expf(st[2]),60000.f);
    float c3=fminf(__expf(st[3]),60000.f);
    h4_t bp = __builtin_bit_cast(h4_t, make_uint2(pkh(c0,c1), pkh(c2,c3)));
    // A=V^T operands: contiguous per-chunk tiles
    h4_t av0 = vh4[vtile + (size_t)ch*128 + voff0];
    h4_t av1 = vh4[vtile + (size_t)ch*128 + voff1];
    acc0 = mfma16(av0, bp, acc0);
    acc1 = mfma16(av1, bp, acc1);
  }

  // write partials: O^T[comp=4*rowb+r][q=q0w+col]; comps 16..19 from acc1 (rowb==0)
  float* rec = part + (((size_t)bh*NSLOT + z)*64 + wave*16 + col)*20;
  ((float4*)rec)[rowb] = make_float4(acc0[0],acc0[1],acc0[2],acc0[3]);
  if(rowb==0) ((float4*)rec)[4] = make_float4(acc1[0],acc1[1],acc1[2],acc1[3]);
}

// ---- K_C: combine partials + ao + norm + m1 + GP/join + m2 + out ---------
// 64 threads = 2 tokens x 32 lanes (8 channels x 4 quarters).
__global__ void __launch_bounds__(64) k_tail(
    const float* __restrict__ part,
    const float* __restrict__ w_ao_mv, const float* __restrict__ w_ao_s2mv,
    const float* __restrict__ w_ao_m2s, const float* __restrict__ w_ao_s2s,
    const float* __restrict__ b_ao_mv, const float* __restrict__ b_ao_s,
    const float* __restrict__ h_mv, const float* __restrict__ h_s,
    const float* __restrict__ w_m1_mv, const float* __restrict__ w_m1_s2mv,
    const float* __restrict__ w_m1_m2s, const float* __restrict__ w_m1_s2s,
    const float* __restrict__ b_m1_mv, const float* __restrict__ b_m1_s,
    const float* __restrict__ w_m2_mv, const float* __restrict__ w_m2_s2mv,
    const float* __restrict__ b_m2_mv,
    const float* __restrict__ w_out_mv,
    float* __restrict__ out)
{
  __shared__ int   GPI[256]; __shared__ float GPS[256];
  __shared__ int   JNI[256]; __shared__ float JNS[256];
  __shared__ float OS[2*152];
  __shared__ float NS[2*152];
  __shared__ float U[2*264];
  __shared__ float G[2*136];
  __shared__ float GSm[2*24];
  int tid=threadIdx.x, tl=tid>>5, ln=tid&31;
  int o=ln&7, iq=ln>>3;          // iq 0..3
  int tt=blockIdx.x*2+tl;

  { // build tables (threads 0..31)
    const int mask_of[16]={0,1,2,4,8,3,5,9,6,10,12,7,11,13,14,15};
    const int idx_of[16] ={0,1,2,5,3,6,8,11,4,7,9,12,10,13,14,15};
    if (tid<16){
      int k=tid, km=mask_of[k], slotn=0;
      for(int i=0;i<16;i++){
        int im=mask_of[i], jm=im^km;
        if(im & jm & 1) continue;
        GPI[k*16+slotn]=i|(idx_of[jm]<<4);
        GPS[k*16+slotn]=(float)rsign_d(im,jm);
        slotn++;
      }
      for(;slotn<16;slotn++){ GPI[k*16+slotn]=0; GPS[k*16+slotn]=0.f; }
    } else if (tid<32){
      int p=tid-16, pm=mask_of[p], rest=15&~pm, slotn=0;
      for(int u=0;u<16;u++){
        if(u & ~rest) continue;
        int am=pm|u, bm=pm|(rest&~u);
        float s=(float)( rsign_d(pm,15&~pm)*rsign_d(15&~am,15&~bm)
                        *rsign_d(am,15&~am)*rsign_d(bm,15&~bm) );
        JNI[p*16+slotn]=idx_of[am]|(idx_of[bm]<<4);
        JNS[p*16+slotn]=s;
        slotn++;
      }
      for(;slotn<16;slotn++){ JNI[p*16+slotn]=0; JNS[p*16+slotn]=0.f; }
    }
  }

  // combine attention partials: lane = (head h=ln>>2, quarter qr=ln&3)
  // strips of 64 queries; aa=strip>>3, nsp=aa+1, rbase=4aa(aa+1)+(strip&7)(aa+1)
  {
    int b=tt>>11, t=tt&(T_-1);
    int strip=t>>6, qil=t&63;
    int h=ln>>2, qr=ln&3;
    int aa=strip>>3;
    int nsp=aa+1;
    int rbase=4*aa*(aa+1)+(strip&7)*(aa+1);
    const float* pb = part + ((size_t)((b*8+h)*NSLOT+rbase)*64 + qil)*20;
    float am[4]={0,0,0,0};
    float lv=0.f, s0=0.f, s1=0.f, s2=0.f;
    for(int spp=0; spp<nsp; ++spp){
      const float4* p4=(const float4*)(pb + (size_t)spp*64*20);
      float4 a4=p4[qr];
      am[0]+=a4.x; am[1]+=a4.y; am[2]+=a4.z; am[3]+=a4.w;
      if(qr==0){ float4 meta=p4[4]; s0+=meta.x; s1+=meta.y; s2+=meta.z; lv+=meta.w; }
    }
    float inv = (qr==0)? 1.f/lv : 0.f;
    inv = __shfl(inv, (tid & ~3));
    float* os=&OS[tl*152];
    #pragma unroll
    for(int p=0;p<4;p++) os[h*16+qr*4+p]=am[p]*inv;
    if(qr==0){ os[128+h*3]=s0*inv; os[128+h*3+1]=s1*inv; os[128+h*3+2]=s2*inv; }
  }
  __syncthreads();

  const float* os=&OS[tl*152];
  float xh[2][16];
  #pragma unroll
  for(int ii=0;ii<2;ii++){
    #pragma unroll
    for(int p=0;p<16;p++) xh[ii][p]=os[(iq*2+ii)*16+p];
  }
  float xs[24];
  #pragma unroll
  for(int jj=0;jj<24;jj++) xs[jj]=os[128+jj];

  // ao: channel o, input quarter iq
  float y[16];
  #pragma unroll
  for(int p=0;p<16;p++) y[p]=0.f;
  #pragma unroll
  for(int ii=0;ii<2;ii++){
    const float* wi=w_ao_mv+o*72+(iq*2+ii)*9;
    #pragma unroll
    for(int p=0;p<16;p++){
      y[p]+=wi[GRADE[p]]*xh[ii][p];
      if(AUGK[p]>=0) y[p]+=wi[AUGK[p]]*xh[ii][AUGS[p]];
    }
  }
  float e=(iq==0)? b_ao_mv[o] : 0.f;
  for(int j2=iq*6;j2<iq*6+6;j2++) e+=w_ao_s2mv[o*24+j2]*xs[j2];
  y[0]+=e;
  float a3[3];
  #pragma unroll
  for(int jj=0;jj<3;jj++) a3[jj]=(iq==0)? b_ao_s[o*3+jj] : 0.f;
  #pragma unroll
  for(int ii=0;ii<2;ii++){
    #pragma unroll
    for(int jj=0;jj<3;jj++) a3[jj]+=w_ao_m2s[(o*3+jj)*8+(iq*2+ii)]*xh[ii][0];
  }
  for(int j2=iq*6;j2<iq*6+6;j2++){
    #pragma unroll
    for(int jj=0;jj<3;jj++) a3[jj]+=w_ao_s2s[(o*3+jj)*24+j2]*xs[j2];
  }
  #pragma unroll
  for(int p=0;p<16;p++){ y[p]+=__shfl_xor(y[p],8); y[p]+=__shfl_xor(y[p],16); }
  #pragma unroll
  for(int jj=0;jj<3;jj++){ a3[jj]+=__shfl_xor(a3[jj],8); a3[jj]+=__shfl_xor(a3[jj],16); }

  // residual + norms (dup across iq; reduce over o via xor 1,2,4)
  float hch[16]; float sqv=0.f;
  { const float4* hg=(const float4*)(h_mv+(size_t)tt*128+o*16);
    #pragma unroll
    for(int r4=0;r4<4;r4++){ float4 v=hg[r4];
      hch[r4*4]=v.x+y[r4*4]; hch[r4*4+1]=v.y+y[r4*4+1];
      hch[r4*4+2]=v.z+y[r4*4+2]; hch[r4*4+3]=v.w+y[r4*4+3]; } }
  #pragma unroll
  for(int p=0;p<16;p++) sqv+=FINNER[p]*hch[p]*hch[p];
  sqv+=__shfl_xor(sqv,1); sqv+=__shfl_xor(sqv,2); sqv+=__shfl_xor(sqv,4);
  float dmv=rsqrtf(sqv*0.125f+0.01f);
  float hs3[3]; float ssq=0.f;
  #pragma unroll
  for(int jj=0;jj<3;jj++){
    float v=h_s[(size_t)tt*24+o*3+jj]+a3[jj];
    hs3[jj]=v; ssq+=v*v;
  }
  ssq+=__shfl_xor(ssq,1); ssq+=__shfl_xor(ssq,2); ssq+=__shfl_xor(ssq,4);
  float dss=rsqrtf(ssq*(1.f/24.f)+0.01f);

  float* nsbuf=&NS[tl*152];
  if(iq==0){
    #pragma unroll
    for(int p=0;p<16;p++) nsbuf[o*16+p]=hch[p]*dmv;
    #pragma unroll
    for(int jj=0;jj<3;jj++) nsbuf[128+o*3+jj]=hs3[jj]*dss;
  }
  __syncthreads();

  // m1: lane = (output channel ln16, input half mh)
  {
    int ln16=ln&15, mh=ln>>4;
    float u[16];
    #pragma unroll
    for(int p=0;p<16;p++) u[p]=0.f;
    for(int i=mh*4;i<mh*4+4;i++){
      float xi[16];
      const float4* xs4=(const float4*)&nsbuf[i*16];
      #pragma unroll
      for(int r4=0;r4<4;r4++){ float4 v=xs4[r4]; xi[r4*4]=v.x; xi[r4*4+1]=v.y; xi[r4*4+2]=v.z; xi[r4*4+3]=v.w; }
      const float* wi=w_m1_mv+ln16*72+i*9;
      #pragma unroll
      for(int p=0;p<16;p++){
        u[p]+=wi[GRADE[p]]*xi[p];
        if(AUGK[p]>=0) u[p]+=wi[AUGK[p]]*xi[AUGS[p]];
      }
    }
    float e1=(mh==0)? b_m1_mv[ln16] : 0.f;
    for(int j2=mh*12;j2<mh*12+12;j2++) e1+=w_m1_s2mv[ln16*24+j2]*nsbuf[128+j2];
    u[0]+=e1;
    #pragma unroll
    for(int p=0;p<16;p++) u[p]+=__shfl_xor(u[p],16);
    if(mh==0){
      float* uu=&U[tl*264];
      #pragma unroll
      for(int p=0;p<16;p++) uu[ln16*16+p]=u[p];
    }
  }
  if(ln<8){  // m1 scalar path, o=ln
    float s3[3];
    #pragma unroll
    for(int jj=0;jj<3;jj++) s3[jj]=b_m1_s[o*3+jj];
    for(int j2=0;j2<24;j2++){
      float s=nsbuf[128+j2];
      #pragma unroll
      for(int jj=0;jj<3;jj++) s3[jj]+=w_m1_s2s[(o*3+jj)*24+j2]*s;
    }
    for(int i=0;i<8;i++){
      float x0=nsbuf[i*16];
      #pragma unroll
      for(int jj=0;jj<3;jj++) s3[jj]+=w_m1_m2s[(o*3+jj)*8+i]*x0;
    }
    #pragma unroll
    for(int jj=0;jj<3;jj++) GSm[tl*24+o*3+jj]=gelu_f(s3[jj]);
  }
  __syncthreads();

  // GP (o<4) / JOIN (o>=4): product o, component quarter iq; gate via shfl
  {
    const int*   TI=(o<4)? GPI : JNI;
    const float* TS=(o<4)? GPS : JNS;
    const float* uu=&U[tl*264];
    const float* lft=&uu[((o<4)? o : (4+o))*16];
    const float* rgt=&uu[((o<4)? (4+o) : (8+o))*16];
    float g[4];
    #pragma unroll
    for(int kk=0;kk<4;kk++){
      int k=iq*4+kk;
      float accv=0.f;
      #pragma unroll
      for(int e2=0;e2<16;e2++){
        int ij=TI[k*16+e2]; float sg=TS[k*16+e2];
        accv += sg * lft[ij&15] * rgt[ij>>4];
      }
      g[kk]=accv;
    }
    float g0 = __shfl(g[0], (tid & ~0x18));   // comp0 lives on iq==0 lane
    float gt = gelu_f(g0);
    float* gg=&G[tl*136];
    #pragma unroll
    for(int kk=0;kk<4;kk++) gg[o*16+iq*4+kk]=g[kk]*gt;
  }
  __syncthreads();

  // m2: channel o, input quarter iq
  float y2[16];
  #pragma unroll
  for(int p=0;p<16;p++) y2[p]=0.f;
  #pragma unroll
  for(int ii=0;ii<2;ii++){
    float xi[16];
    const float4* gi=(const float4*)&G[tl*136+(iq*2+ii)*16];
    #pragma unroll
    for(int r4=0;r4<4;r4++){ float4 v=gi[r4]; xi[r4*4]=v.x; xi[r4*4+1]=v.y; xi[r4*4+2]=v.z; xi[r4*4+3]=v.w; }
    const float* wi=w_m2_mv+o*72+(iq*2+ii)*9;
    #pragma unroll
    for(int p=0;p<16;p++){
      y2[p]+=wi[GRADE[p]]*xi[p];
      if(AUGK[p]>=0) y2[p]+=wi[AUGK[p]]*xi[AUGS[p]];
    }
  }
  float e2=(iq==0)? b_m2_mv[o] : 0.f;
  for(int j2=iq*6;j2<iq*6+6;j2++) e2+=w_m2_s2mv[o*24+j2]*GSm[tl*24+j2];
  y2[0]+=e2;
  #pragma unroll
  for(int p=0;p<16;p++){ y2[p]+=__shfl_xor(y2[p],8); y2[p]+=__shfl_xor(y2[p],16); }

  float hf[16];
  #pragma unroll
  for(int p=0;p<16;p++) hf[p]=hch[p]+y2[p];

  const float* wout=w_out_mv+o*9;
  float c5 =wout[2]*hf[5] +wout[6]*hf[2];
  float c6 =wout[2]*hf[6] +wout[6]*hf[3];
  float c7 =wout[2]*hf[7] +wout[6]*hf[4];
  float c11=wout[3]*hf[11]+wout[7]*hf[8];
  float c12=wout[3]*hf[12]+wout[7]*hf[9];
  float c13=wout[3]*hf[13]+wout[7]*hf[10];
  float c14=wout[3]*hf[14];
  #pragma unroll
  for(int mk=1; mk<8; mk<<=1){
    c5+=__shfl_xor(c5,mk); c6+=__shfl_xor(c6,mk); c7+=__shfl_xor(c7,mk);
    c11+=__shfl_xor(c11,mk); c12+=__shfl_xor(c12,mk);
    c13+=__shfl_xor(c13,mk); c14+=__shfl_xor(c14,mk);
  }
  if(ln==0){
    float dd=c14;
    dd=(fabsf(dd)>0.001f)? dd : (dd>=0.f? 0.001f : -0.001f);
    float* op=out+(size_t)tt*6;
    op[0]=-c13/dd; op[1]=c12/dd; op[2]=-c11/dd;
    op[3]=2.f*c5; op[4]=2.f*c6; op[5]=2.f*c7;
  }
}

extern "C" void kernel_launch(void* const* d_in, const int* in_sizes, int n_in,
                              void* d_out, int out_size, void* d_ws, size_t ws_size,
                              hipStream_t stream)
{
  (void)in_sizes; (void)n_in; (void)out_size; (void)ws_size;
  const float* x         =(const float*)d_in[0];
  const float* w_in_mv   =(const float*)d_in[1];
  const float* b_in_mv   =(const float*)d_in[2];
  const float* w_in_m2s  =(const float*)d_in[3];
  const float* b_in_s    =(const float*)d_in[4];
  const float* w_qkv_mv  =(const float*)d_in[5];
  const float* w_qkv_s2mv=(const float*)d_in[6];
  const float* w_qkv_m2s =(const float*)d_in[7];
  const float* w_qkv_s2s =(const float*)d_in[8];
  const float* w_ao_mv   =(const float*)d_in[9];
  const float* w_ao_s2mv =(const float*)d_in[10];
  const float* w_ao_m2s  =(const float*)d_in[11];
  const float* w_ao_s2s  =(const float*)d_in[12];
  const float* b_ao_mv   =(const float*)d_in[13];
  const float* b_ao_s    =(const float*)d_in[14];
  const float* w_m1_mv   =(const float*)d_in[15];
  const float* w_m1_s2mv =(const float*)d_in[16];
  const float* w_m1_m2s  =(const float*)d_in[17];
  const float* w_m1_s2s  =(const float*)d_in[18];
  const float* b_m1_mv   =(const float*)d_in[19];
  const float* b_m1_s    =(const float*)d_in[20];
  const float* w_m2_mv   =(const float*)d_in[21];
  const float* w_m2_s2mv =(const float*)d_in[22];
  const float* b_m2_mv   =(const float*)d_in[25];
  const float* w_out_mv  =(const float*)d_in[27];
  float* outp=(float*)d_out;

  float* ws=(float*)d_ws;
  size_t off=0;
  float* h_mv = ws+off; off+=(size_t)BTOK*128;
  float* h_s  = ws+off; off+=(size_t)BTOK*24;
  unsigned* qph = (unsigned*)(ws+off); off+=(size_t)16*T_*8;        // 16 halfs/token
  unsigned* kph = (unsigned*)(ws+off); off+=(size_t)16*T_*8;        // 16 halfs/token
  unsigned* vph = (unsigned*)(ws+off); off+=(size_t)16*(T_/16)*256; // V^T chunk tiles
  float* part = ws+off; off+=(size_t)16*NSLOT*64*20;

  k_in  <<<BTOK/2,64,0,stream>>>(x,w_in_mv,b_in_mv,w_in_m2s,b_in_s,
                                 w_qkv_mv,w_qkv_s2mv,w_qkv_m2s,w_qkv_s2s,
                                 h_mv,h_s,qph,kph,vph);
  k_attn<<<16*NSLOT,256,0,stream>>>(qph,kph,vph,part);
  k_tail<<<BTOK/2,64,0,stream>>>(part,
                                 w_ao_mv,w_ao_s2mv,w_ao_m2s,w_ao_s2s,b_ao_mv,b_ao_s,
                                 h_mv,h_s,
                                 w_m1_mv,w_m1_s2mv,w_m1_m2s,w_m1_s2s,b_m1_mv,b_m1_s,
                                 w_m2_mv,w_m2_s2mv,b_m2_mv,w_out_mv,outp);
}